// Round 6
// baseline (941.292 us; speedup 1.0000x reference)
//
#include <hip/hip_runtime.h>
#include <hip/hip_bf16.h>

#define NPTS 65536
#define NSAMP 16
#define CH 256
#define CNT (NPTS * NSAMP)   // 1048576
#define EPSV 1e-5f

typedef __hip_bfloat16 bf16;
typedef __attribute__((ext_vector_type(8))) short short8;
typedef __attribute__((ext_vector_type(4))) short sh4;
typedef __attribute__((ext_vector_type(4))) float floatx4;

__device__ __forceinline__ float b2f(bf16 v) { return __bfloat162float(v); }

// bf16 bits (as short) -> float
__device__ __forceinline__ float s2f(short v) {
    return __uint_as_float(((unsigned)(unsigned short)v) << 16);
}

__device__ __forceinline__ short f2bf_bits(float f) {
    bf16 h = __float2bfloat16(f);
    short s;
    __builtin_memcpy(&s, &h, 2);
    return s;
}

// ---------------------------------------------------------------------------
// convw: blocks 0..95 pack wq|wk|wv (f32) into Wcat[768*256] bf16; block 96
// converts ww2 (32x32) to bf16; blocks 97.. convert x (65536x256 f32) to xb
// bf16 (aliased onto the y2 workspace region - dead until stats2 writes y2).
// ---------------------------------------------------------------------------
__global__ __launch_bounds__(256) void convw_kernel(
    const float* __restrict__ wq, const float* __restrict__ wk,
    const float* __restrict__ wv, const float* __restrict__ ww2,
    const float* __restrict__ x,
    bf16* __restrict__ Wcat, bf16* __restrict__ ww2b, bf16* __restrict__ xb)
{
    if (blockIdx.x < 96) {
        int e = (blockIdx.x * 256 + threadIdx.x) * 8;   // e < 196608
        const float* src = (e < 65536) ? wq : (e < 131072) ? wk : wv;
        int off = e & 65535;
        float4 f0 = *(const float4*)(src + off);
        float4 f1 = *(const float4*)(src + off + 4);
        short8 r;
        r[0] = f2bf_bits(f0.x); r[1] = f2bf_bits(f0.y);
        r[2] = f2bf_bits(f0.z); r[3] = f2bf_bits(f0.w);
        r[4] = f2bf_bits(f1.x); r[5] = f2bf_bits(f1.y);
        r[6] = f2bf_bits(f1.z); r[7] = f2bf_bits(f1.w);
        *(short8*)(Wcat + e) = r;
    } else if (blockIdx.x == 96) {
        int e = threadIdx.x * 4;   // 256*4 = 1024 = 32*32
        float4 f = *(const float4*)(ww2 + e);
        sh4 r;
        r[0] = f2bf_bits(f.x); r[1] = f2bf_bits(f.y);
        r[2] = f2bf_bits(f.z); r[3] = f2bf_bits(f.w);
        *(sh4*)(ww2b + e) = r;
    } else {
        // x -> bf16: 16,777,216 elements, 8 per thread, 8192 blocks
        size_t e = ((size_t)(blockIdx.x - 97) * 256 + threadIdx.x) * 8;
        float4 f0 = *(const float4*)(x + e);
        float4 f1 = *(const float4*)(x + e + 4);
        short8 r;
        r[0] = f2bf_bits(f0.x); r[1] = f2bf_bits(f0.y);
        r[2] = f2bf_bits(f0.z); r[3] = f2bf_bits(f0.w);
        r[4] = f2bf_bits(f1.x); r[5] = f2bf_bits(f1.y);
        r[6] = f2bf_bits(f1.z); r[7] = f2bf_bits(f1.w);
        *(short8*)(xb + e) = r;
    }
}

// ---------------------------------------------------------------------------
// gemm: C[65536 x 768] = xb(bf16) @ Wcat^T, written as xq|xk|xv bf16 slices.
// 128x128 tiles, BK=32, LDS stride 40 (pad), 4 waves each 64x64.
// A-staging is now a pure bf16 copy (x pre-converted once in convw).
// ---------------------------------------------------------------------------
__global__ __launch_bounds__(256) void gemm_kernel(
    const bf16* __restrict__ xb, const bf16* __restrict__ Wcat,
    const float* __restrict__ bq, const float* __restrict__ bk,
    const float* __restrict__ bv,
    bf16* __restrict__ xq, bf16* __restrict__ xk, bf16* __restrict__ xv)
{
    __shared__ __align__(16) bf16 As[128 * 40];
    __shared__ __align__(16) bf16 Bs[128 * 40];

    int t = threadIdx.x, lane = t & 63, wave = t >> 6;
    int m0 = blockIdx.x * 128;
    int y = blockIdx.y, n0 = y * 128;
    int srow = t >> 1, sch = t & 1;       // staging: 2 threads per row, 16 elems each
    int m = lane & 15, q = lane >> 4;
    int wm = wave >> 1, wn = wave & 1;

    floatx4 acc[4][4];
#pragma unroll
    for (int a = 0; a < 4; a++)
#pragma unroll
        for (int b = 0; b < 4; b++) acc[a][b] = (floatx4){0.f, 0.f, 0.f, 0.f};

    for (int kk = 0; kk < 256; kk += 32) {
        // stage A (bf16 copy)
        const bf16* ap = xb + (size_t)(m0 + srow) * 256 + kk + sch * 16;
        *(short8*)&As[srow * 40 + sch * 16]     = *(const short8*)ap;
        *(short8*)&As[srow * 40 + sch * 16 + 8] = *(const short8*)(ap + 8);
        // stage B (bf16 copy)
        const bf16* bp = Wcat + (size_t)(n0 + srow) * 256 + kk + sch * 16;
        *(short8*)&Bs[srow * 40 + sch * 16]     = *(const short8*)bp;
        *(short8*)&Bs[srow * 40 + sch * 16 + 8] = *(const short8*)(bp + 8);
        __syncthreads();

        short8 av[4], bvv[4];
#pragma unroll
        for (int mt = 0; mt < 4; mt++)
            av[mt] = *(const short8*)&As[(wm * 64 + mt * 16 + m) * 40 + q * 8];
#pragma unroll
        for (int nt = 0; nt < 4; nt++)
            bvv[nt] = *(const short8*)&Bs[(wn * 64 + nt * 16 + m) * 40 + q * 8];
#pragma unroll
        for (int mt = 0; mt < 4; mt++)
#pragma unroll
            for (int nt = 0; nt < 4; nt++)
                acc[mt][nt] = __builtin_amdgcn_mfma_f32_16x16x32_bf16(av[mt], bvv[nt], acc[mt][nt], 0, 0, 0);
        __syncthreads();
    }

    int z = y >> 1;
    bf16* O        = (z == 0) ? xq : (z == 1) ? xk : xv;
    const float* B = (z == 0) ? bq : (z == 1) ? bk : bv;
    int cbase = (y & 1) * 128 + wn * 64;
#pragma unroll
    for (int nt = 0; nt < 4; nt++) {
        int oc = cbase + nt * 16 + m;
        float bias = B[oc];
#pragma unroll
        for (int mt = 0; mt < 4; mt++) {
            int grow = m0 + wm * 64 + mt * 16 + q * 4;
#pragma unroll
            for (int i = 0; i < 4; i++)
                O[(size_t)(grow + i) * 256 + oc] = __float2bfloat16(acc[mt][nt][i] + bias);
        }
    }
}

// ---------------------------------------------------------------------------
// statsp: BN_p stats over p_r1 = (p[idx]-p) @ wp1^T + bp1   (3 channels).
// Also caches the pre-BN vector v into v4[r] so computer_kernel does not
// need to re-gather p[idx] (it becomes an in-place streaming transform).
// ---------------------------------------------------------------------------
__global__ __launch_bounds__(256) void statsp_kernel(
    const float* __restrict__ p, const int* __restrict__ idx,
    const float* __restrict__ wp1, const float* __restrict__ bp1,
    float* __restrict__ statsP, float4* __restrict__ v4)
{
    float W00 = wp1[0], W01 = wp1[1], W02 = wp1[2];
    float W10 = wp1[3], W11 = wp1[4], W12 = wp1[5];
    float W20 = wp1[6], W21 = wp1[7], W22 = wp1[8];
    float B0 = bp1[0], B1 = bp1[1], B2 = bp1[2];

    float s0 = 0, s1 = 0, s2 = 0, q0 = 0, q1 = 0, q2 = 0;
    int stride = gridDim.x * blockDim.x;
    for (int r = blockIdx.x * blockDim.x + threadIdx.x; r < CNT; r += stride) {
        int n = r >> 4;
        int i = idx[r];
        float a0 = p[3 * (size_t)i]     - p[3 * (size_t)n];
        float a1 = p[3 * (size_t)i + 1] - p[3 * (size_t)n + 1];
        float a2 = p[3 * (size_t)i + 2] - p[3 * (size_t)n + 2];
        float v0 = W00 * a0 + W01 * a1 + W02 * a2 + B0;
        float v1 = W10 * a0 + W11 * a1 + W12 * a2 + B1;
        float v2 = W20 * a0 + W21 * a1 + W22 * a2 + B2;
        s0 += v0; q0 += v0 * v0;
        s1 += v1; q1 += v1 * v1;
        s2 += v2; q2 += v2 * v2;
        v4[r] = make_float4(v0, v1, v2, 0.f);
    }
    float v[6] = {s0, s1, s2, q0, q1, q2};
#pragma unroll
    for (int k = 0; k < 6; k++) {
        float xv = v[k];
#pragma unroll
        for (int off = 32; off > 0; off >>= 1) xv += __shfl_down(xv, off);
        if ((threadIdx.x & 63) == 0) atomicAdd(&statsP[k], xv);
    }
}

// ---------------------------------------------------------------------------
// finalize: mean/var -> scale/shift
// ---------------------------------------------------------------------------
__global__ void finalize_kernel(const float* __restrict__ stats,
                                const float* __restrict__ gamma,
                                const float* __restrict__ beta,
                                float* __restrict__ ss, int nch)
{
    int c = threadIdx.x;
    if (c < nch) {
        float inv = 1.0f / (float)CNT;
        float mean = stats[c] * inv;
        float var = stats[nch + c] * inv - mean * mean;
        float sc = gamma[c] * rsqrtf(var + EPSV);
        ss[c] = sc;
        ss[nch + c] = beta[c] - mean * sc;
    }
}

// ---------------------------------------------------------------------------
// computer: r4[r] = relu(BN_p(v4[r])) in place (pure streaming transform;
// the p_r1 vector was cached by statsp).
// ---------------------------------------------------------------------------
__global__ __launch_bounds__(256) void computer_kernel(
    const float* __restrict__ ssP, float4* __restrict__ r4)
{
    float sc0 = ssP[0], sc1 = ssP[1], sc2 = ssP[2];
    float sh0 = ssP[3], sh1 = ssP[4], sh2 = ssP[5];

    int stride = gridDim.x * blockDim.x;
    for (int r = blockIdx.x * blockDim.x + threadIdx.x; r < CNT; r += stride) {
        float4 v = r4[r];
        float v0 = fmaxf(sc0 * v.x + sh0, 0.f);
        float v1 = fmaxf(sc1 * v.y + sh1, 0.f);
        float v2 = fmaxf(sc2 * v.z + sh2, 0.f);
        r4[r] = make_float4(v0, v1, v2, 0.f);
    }
}

// ---------------------------------------------------------------------------
// stats1: BN1 stats over w = xk[idx] - xq + p_r2.  Thread = 8 channels,
// short8 gathers, LDS block-reduce, 2 atomics/thread-channel.
// ---------------------------------------------------------------------------
__global__ __launch_bounds__(256) void stats1_kernel(
    const int* __restrict__ idx, const float4* __restrict__ r4,
    const bf16* __restrict__ xk, const bf16* __restrict__ xq,
    const float* __restrict__ wp2, const float* __restrict__ bp2,
    float* __restrict__ stats1)
{
    __shared__ int idxs[1024];
    __shared__ float redS[8 * 264];
    __shared__ float redQ[8 * 264];

    int t = threadIdx.x;
    int r0 = blockIdx.x * 1024;
    for (int e = t; e < 1024; e += 256) idxs[e] = idx[r0 + e];

    int sub = t & 31, rl = t >> 5, cb = sub * 8;
    float w0[8], w1[8], w2[8], bc[8];
#pragma unroll
    for (int k = 0; k < 8; k++) {
        w0[k] = wp2[3 * (cb + k)];
        w1[k] = wp2[3 * (cb + k) + 1];
        w2[k] = wp2[3 * (cb + k) + 2];
        bc[k] = bp2[cb + k];
    }
    float s8[8] = {0, 0, 0, 0, 0, 0, 0, 0};
    float q8[8] = {0, 0, 0, 0, 0, 0, 0, 0};
    __syncthreads();

#pragma unroll 4
    for (int rr = rl; rr < 1024; rr += 8) {
        int r = r0 + rr;
        int i = idxs[rr];
        float4 rv = r4[r];
        short8 kv = *(const short8*)(xk + (size_t)i * 256 + cb);
        short8 qv = *(const short8*)(xq + (size_t)(r >> 4) * 256 + cb);
#pragma unroll
        for (int k = 0; k < 8; k++) {
            float w = s2f(kv[k]) - s2f(qv[k]) + rv.x * w0[k] + rv.y * w1[k] + rv.z * w2[k] + bc[k];
            s8[k] += w; q8[k] += w * w;
        }
    }
#pragma unroll
    for (int k = 0; k < 8; k++) {
        redS[rl * 264 + cb + k] = s8[k];
        redQ[rl * 264 + cb + k] = q8[k];
    }
    __syncthreads();
    int c = t;
    float ts = 0, tq = 0;
#pragma unroll
    for (int sr = 0; sr < 8; sr++) {
        ts += redS[sr * 264 + c];
        tq += redQ[sr * 264 + c];
    }
    atomicAdd(&stats1[c], ts);
    atomicAdd(&stats1[256 + c], tq);
}

// ---------------------------------------------------------------------------
// stats2 (single-barrier double-buffer): y2 = relu(BN1(w)) @ ww1^T + bw1
// + BN2 stats. Two 32KB hb buffers, ONE __syncthreads per 64-row tile:
//   A: issue next tile's xk gathers into regs (latency hidden under B)
//   B: MFMA current buffer (ds_read_b128, swizzled) + y2 stores
//   C: load qv/rv, compute h, ds_write next buffer
// ww1 B-fragments in VGPRs; BN1 consts folded in regs.
// ---------------------------------------------------------------------------
__global__ __launch_bounds__(256) void stats2_kernel(
    const int* __restrict__ idx, const float4* __restrict__ r4,
    const bf16* __restrict__ xk, const bf16* __restrict__ xq,
    const float* __restrict__ wp2, const float* __restrict__ bp2,
    const float* __restrict__ ss1,
    const float* __restrict__ ww1, const float* __restrict__ bw1,
    bf16* __restrict__ y2, float* __restrict__ stats2)
{
    __shared__ __align__(16) bf16 hb0[64 * 256];   // XOR-swizzled rows
    __shared__ __align__(16) bf16 hb1[64 * 256];

    int t = threadIdx.x;
    int lane = t & 63, wave = t >> 6;
    int m = lane & 15, q = lane >> 4;
    int sub = t & 31, rl = t >> 5, cb = sub * 8;
    int r0 = blockIdx.x * 1024;

    // ww1 B-fragments -> registers (f32 global, L2-resident, once per block)
    short8 bf0[8], bf1[8];
#pragma unroll
    for (int k = 0; k < 8; k++) {
        const float* w0p = ww1 + m * 256 + k * 32 + q * 8;
        const float* w1p = ww1 + (16 + m) * 256 + k * 32 + q * 8;
        float4 u0 = *(const float4*)(w0p);
        float4 u1 = *(const float4*)(w0p + 4);
        float4 u2 = *(const float4*)(w1p);
        float4 u3 = *(const float4*)(w1p + 4);
        short8 b0, b1;
        b0[0] = f2bf_bits(u0.x); b0[1] = f2bf_bits(u0.y);
        b0[2] = f2bf_bits(u0.z); b0[3] = f2bf_bits(u0.w);
        b0[4] = f2bf_bits(u1.x); b0[5] = f2bf_bits(u1.y);
        b0[6] = f2bf_bits(u1.z); b0[7] = f2bf_bits(u1.w);
        b1[0] = f2bf_bits(u2.x); b1[1] = f2bf_bits(u2.y);
        b1[2] = f2bf_bits(u2.z); b1[3] = f2bf_bits(u2.w);
        b1[4] = f2bf_bits(u3.x); b1[5] = f2bf_bits(u3.y);
        b1[6] = f2bf_bits(u3.z); b1[7] = f2bf_bits(u3.w);
        bf0[k] = b0; bf1[k] = b1;
    }

    float w0[8], w1[8], w2[8], bc[8], s1c[8], t1c[8];
#pragma unroll
    for (int k = 0; k < 8; k++) {
        w0[k] = wp2[3 * (cb + k)];
        w1[k] = wp2[3 * (cb + k) + 1];
        w2[k] = wp2[3 * (cb + k) + 2];
        bc[k] = bp2[cb + k];
        s1c[k] = ss1[cb + k];
        t1c[k] = ss1[256 + cb + k];
    }
    float bw0 = bw1[m], bw16 = bw1[16 + m];
    float jsum0 = 0, jsum1 = 0, jsq0 = 0, jsq1 = 0;
    int swh = cb ^ (rl << 3);        // staging write col (rr&7 == rl, const)
    int swa = (m & 7) << 3;          // MFMA read XOR ((wave*16+m)&7 == m&7)

    // prologue: stage tile 0 into hb0 (combined load+compute+write)
    {
#pragma unroll
        for (int u = 0; u < 8; u++) {
            int rr = rl + u * 8;
            int r = r0 + rr;
            int i = idx[r];
            float4 rv = r4[r];
            short8 kv = *(const short8*)(xk + (size_t)i * 256 + cb);
            short8 qv = *(const short8*)(xq + (size_t)(r >> 4) * 256 + cb);
            short8 h;
#pragma unroll
            for (int k = 0; k < 8; k++) {
                float w = s2f(kv[k]) - s2f(qv[k]) + rv.x * w0[k] + rv.y * w1[k] + rv.z * w2[k] + bc[k];
                h[k] = f2bf_bits(fmaxf(s1c[k] * w + t1c[k], 0.f));
            }
            *(short8*)&hb0[rr * 256 + swh] = h;
        }
    }

    for (int it = 0; it < 16; ++it) {
        __syncthreads();   // staging of tile `it` complete (from prev iter / prologue)

        int rbn = r0 + (it + 1) * 64;
        bf16* hbw = (it & 1) ? hb0 : hb1;                 // next buffer
        const bf16* abase = ((it & 1) ? hb1 : hb0) + (wave * 16 + m) * 256;

        // A: issue next tile's random xk gathers (latency hides under B)
        short8 kvs[8];
        if (it < 15) {
#pragma unroll
            for (int u = 0; u < 8; u++) {
                int r = rbn + rl + u * 8;
                kvs[u] = *(const short8*)(xk + (size_t)idx[r] * 256 + cb);
            }
        }

        // B: MFMA from current buffer + y2 stores
        floatx4 a0 = (floatx4){bw0, bw0, bw0, bw0};
        floatx4 a1 = (floatx4){bw16, bw16, bw16, bw16};
#pragma unroll
        for (int k = 0; k < 8; k++) {
            int col = (k * 32 + q * 8) ^ swa;
            short8 af = *(const short8*)(abase + col);
            a0 = __builtin_amdgcn_mfma_f32_16x16x32_bf16(af, bf0[k], a0, 0, 0, 0);
            a1 = __builtin_amdgcn_mfma_f32_16x16x32_bf16(af, bf1[k], a1, 0, 0, 0);
        }
        int grow = r0 + it * 64 + wave * 16 + q * 4;
#pragma unroll
        for (int ii = 0; ii < 4; ii++) {
            float y0 = a0[ii];
            float y1 = a1[ii];
            jsum0 += y0; jsq0 += y0 * y0;
            jsum1 += y1; jsq1 += y1 * y1;
            y2[(size_t)(grow + ii) * 32 + m]      = __float2bfloat16(y0);
            y2[(size_t)(grow + ii) * 32 + 16 + m] = __float2bfloat16(y1);
        }

        // C: finish next tile's rows (cache-friendly loads) and write to LDS
        if (it < 15) {
#pragma unroll
            for (int u = 0; u < 8; u++) {
                int rr = rl + u * 8;
                int r = rbn + rr;
                float4 rv = r4[r];
                short8 qv = *(const short8*)(xq + (size_t)(r >> 4) * 256 + cb);
                short8 h;
#pragma unroll
                for (int k = 0; k < 8; k++) {
                    float w = s2f(kvs[u][k]) - s2f(qv[k]) + rv.x * w0[k] + rv.y * w1[k] + rv.z * w2[k] + bc[k];
                    h[k] = f2bf_bits(fmaxf(s1c[k] * w + t1c[k], 0.f));
                }
                *(short8*)&hbw[rr * 256 + swh] = h;
            }
        }
    }

    jsum0 += __shfl_xor(jsum0, 16); jsum0 += __shfl_xor(jsum0, 32);
    jsum1 += __shfl_xor(jsum1, 16); jsum1 += __shfl_xor(jsum1, 32);
    jsq0  += __shfl_xor(jsq0, 16);  jsq0  += __shfl_xor(jsq0, 32);
    jsq1  += __shfl_xor(jsq1, 16);  jsq1  += __shfl_xor(jsq1, 32);
    if (q == 0) {
        atomicAdd(&stats2[m], jsum0);
        atomicAdd(&stats2[16 + m], jsum1);
        atomicAdd(&stats2[32 + m], jsq0);
        atomicAdd(&stats2[48 + m], jsq1);
    }
}

// ---------------------------------------------------------------------------
// final: wave-per-point, zero barriers.
//  - logits lb[16s x 32j] = bn2relu(y2) @ ww2b^T via 2 MFMAs (C init = bias)
//  - softmax over s fully in-register (shfl_xor 16/32 column reduce)
//  - pr2 term factored: sum_s pr2[s,c]*w[s,j] = sum_d wp2[c,d]*A[d,j]
//    + bp2[c]*A[3,j], A[d,j] = sum_s rr[s,d]*w[s,j]  (in-reg shfl reduce)
//  - phase D: lane owns 4 channels, loops 16 neighbors; xv gather 8B/lane,
//    w[s,j] via float4 LDS read (conflict-free), idx broadcast via readlane.
// Each wave handles 8 points; 4 independent waves per block; grid 2048.
// ---------------------------------------------------------------------------
__global__ __launch_bounds__(256) void final_kernel(
    const int* __restrict__ idx, const float4* __restrict__ r4,
    const bf16* __restrict__ xv,
    const float* __restrict__ wp2, const float* __restrict__ bp2,
    const bf16* __restrict__ y2, const float* __restrict__ ss2,
    const bf16* __restrict__ ww2b, const float* __restrict__ bw2,
    float* __restrict__ out)
{
    __shared__ __align__(16) float wsm[4][16][36];  // [wave][s][j] stride 36 (144B, 16-aligned)
    __shared__ float Asm[4][4][32];                 // [wave][d][j]

    int t = threadIdx.x, wave = t >> 6, lane = t & 63;
    int m = lane & 15, q = lane >> 4;

    // logits B-fragments: ww2b rows m / 16+m (output cols), K-span q*8
    short8 bf0 = *(const short8*)(ww2b + m * 32 + q * 8);
    short8 bf1 = *(const short8*)(ww2b + (16 + m) * 32 + q * 8);
    float bwj0 = bw2[m], bwj1 = bw2[16 + m];

    float s2c[8], t2c[8];
#pragma unroll
    for (int k = 0; k < 8; k++) {
        s2c[k] = ss2[q * 8 + k];
        t2c[k] = ss2[32 + q * 8 + k];
    }

    int c0 = lane * 4;          // this lane's 4 output channels
    int j4 = (lane & 7) * 4;    // j = c & 31
    float wpc0[4], wpc1[4], wpc2[4], bpc[4];
#pragma unroll
    for (int k = 0; k < 4; k++) {
        wpc0[k] = wp2[(c0 + k) * 3];
        wpc1[k] = wp2[(c0 + k) * 3 + 1];
        wpc2[k] = wp2[(c0 + k) * 3 + 2];
        bpc[k]  = bp2[c0 + k];
    }

    int pbase = (blockIdx.x * 4 + wave) * 8;
    for (int pp = 0; pp < 8; pp++) {
        int n = pbase + pp;
        size_t rbase = (size_t)n * 16;

        int iv = idx[rbase + m];   // lanes 0..15 hold the 16 neighbor ids

        // A-frag: z[s=m][u=q*8+k] = relu(bn2(y2))
        short8 yv = *(const short8*)(y2 + (rbase + m) * 32 + q * 8);
        short8 av;
#pragma unroll
        for (int k = 0; k < 8; k++)
            av[k] = f2bf_bits(fmaxf(s2c[k] * s2f(yv[k]) + t2c[k], 0.f));

        floatx4 l0 = (floatx4){bwj0, bwj0, bwj0, bwj0};
        floatx4 l1 = (floatx4){bwj1, bwj1, bwj1, bwj1};
        l0 = __builtin_amdgcn_mfma_f32_16x16x32_bf16(av, bf0, l0, 0, 0, 0);
        l1 = __builtin_amdgcn_mfma_f32_16x16x32_bf16(av, bf1, l1, 0, 0, 0);
        // lane (m,q), reg i: l0[i] = lb[s=q*4+i][j=m], l1[i] = lb[s][j=16+m]

        // softmax over s per column j: lanes {m, m+16, m+32, m+48} hold a column
        float mx0 = fmaxf(fmaxf(l0[0], l0[1]), fmaxf(l0[2], l0[3]));
        float mx1 = fmaxf(fmaxf(l1[0], l1[1]), fmaxf(l1[2], l1[3]));
        mx0 = fmaxf(mx0, __shfl_xor(mx0, 16));
        mx0 = fmaxf(mx0, __shfl_xor(mx0, 32));
        mx1 = fmaxf(mx1, __shfl_xor(mx1, 16));
        mx1 = fmaxf(mx1, __shfl_xor(mx1, 32));
        float w0[4], w1[4];
        float sum0 = 0.f, sum1 = 0.f;
#pragma unroll
        for (int i = 0; i < 4; i++) {
            w0[i] = __expf(l0[i] - mx0); sum0 += w0[i];
            w1[i] = __expf(l1[i] - mx1); sum1 += w1[i];
        }
        sum0 += __shfl_xor(sum0, 16); sum0 += __shfl_xor(sum0, 32);
        sum1 += __shfl_xor(sum1, 16); sum1 += __shfl_xor(sum1, 32);
        float inv0 = 1.f / sum0, inv1 = 1.f / sum1;

        // normalize + A[d][j] partials + stash w to LDS
        float A00 = 0, A10 = 0, A20 = 0, A30 = 0;
        float A01 = 0, A11 = 0, A21 = 0, A31 = 0;
#pragma unroll
        for (int i = 0; i < 4; i++) {
            w0[i] *= inv0; w1[i] *= inv1;
            float4 rv = r4[rbase + q * 4 + i];
            A00 += rv.x * w0[i]; A10 += rv.y * w0[i];
            A20 += rv.z * w0[i]; A30 += w0[i];
            A01 += rv.x * w1[i]; A11 += rv.y * w1[i];
            A21 += rv.z * w1[i]; A31 += w1[i];
            wsm[wave][q * 4 + i][m]      = w0[i];
            wsm[wave][q * 4 + i][16 + m] = w1[i];
        }
        A00 += __shfl_xor(A00, 16); A00 += __shfl_xor(A00, 32);
        A10 += __shfl_xor(A10, 16); A10 += __shfl_xor(A10, 32);
        A20 += __shfl_xor(A20, 16); A20 += __shfl_xor(A20, 32);
        A30 += __shfl_xor(A30, 16); A30 += __shfl_xor(A30, 32);
        A01 += __shfl_xor(A01, 16); A01 += __shfl_xor(A01, 32);
        A11 += __shfl_xor(A11, 16); A11 += __shfl_xor(A11, 32);
        A21 += __shfl_xor(A21, 16); A21 += __shfl_xor(A21, 32);
        A31 += __shfl_xor(A31, 16); A31 += __shfl_xor(A31, 32);
        if (q == 0) {
            Asm[wave][0][m] = A00; Asm[wave][1][m] = A10;
            Asm[wave][2][m] = A20; Asm[wave][3][m] = A30;
            Asm[wave][0][16 + m] = A01; Asm[wave][1][16 + m] = A11;
            Asm[wave][2][16 + m] = A21; Asm[wave][3][16 + m] = A31;
        }
        // wave-private LDS: in-order DS pipe + compiler lgkmcnt ordering,
        // no __syncthreads needed.

        // phase D: weighted neighbor sum over the gathered xv rows
        float acc0 = 0, acc1 = 0, acc2 = 0, acc3 = 0;
#pragma unroll
        for (int s = 0; s < 16; s++) {
            int i = __builtin_amdgcn_readlane(iv, s);   // uniform -> SGPR base
            sh4 vv = *(const sh4*)(xv + (size_t)i * 256 + c0);
            float4 wv = *(const float4*)&wsm[wave][s][j4];
            acc0 += s2f(vv[0]) * wv.x;
            acc1 += s2f(vv[1]) * wv.y;
            acc2 += s2f(vv[2]) * wv.z;
            acc3 += s2f(vv[3]) * wv.w;
        }

        float res[4] = {acc0, acc1, acc2, acc3};
#pragma unroll
        for (int k = 0; k < 4; k++) {
            int j = j4 + k;
            res[k] += wpc0[k] * Asm[wave][0][j] + wpc1[k] * Asm[wave][1][j]
                    + wpc2[k] * Asm[wave][2][j] + bpc[k]  * Asm[wave][3][j];
        }
        *(float4*)(out + (size_t)n * 256 + c0) =
            make_float4(res[0], res[1], res[2], res[3]);
    }
}

// ---------------------------------------------------------------------------
extern "C" void kernel_launch(void* const* d_in, const int* in_sizes, int n_in,
                              void* d_out, int out_size, void* d_ws, size_t ws_size,
                              hipStream_t stream) {
    (void)in_sizes; (void)n_in; (void)out_size; (void)ws_size;

    const float* p   = (const float*)d_in[0];
    const float* x   = (const float*)d_in[1];
    const int*   idx = (const int*)d_in[2];
    const float* wq  = (const float*)d_in[3];  const float* bq  = (const float*)d_in[4];
    const float* wk  = (const float*)d_in[5];  const float* bk  = (const float*)d_in[6];
    const float* wv  = (const float*)d_in[7];  const float* bv  = (const float*)d_in[8];
    const float* wp1 = (const float*)d_in[9];  const float* bp1 = (const float*)d_in[10];
    const float* gp  = (const float*)d_in[11]; const float* btp = (const float*)d_in[12];
    const float* wp2 = (const float*)d_in[13]; const float* bp2 = (const float*)d_in[14];
    const float* g1  = (const float*)d_in[15]; const float* b1  = (const float*)d_in[16];
    const float* ww1 = (const float*)d_in[17]; const float* bw1 = (const float*)d_in[18];
    const float* g2  = (const float*)d_in[19]; const float* b2  = (const float*)d_in[20];
    const float* ww2 = (const float*)d_in[21]; const float* bw2 = (const float*)d_in[22];
    float* out = (float*)d_out;

    // workspace layout
    float* fws    = (float*)d_ws;
    float* statsP = fws;            // 6  (8 slots)
    float* ssP    = fws + 8;        // 6  (8 slots)
    float* stats1 = fws + 16;       // 512
    float* ss1    = fws + 528;      // 512
    float* stats2 = fws + 1040;     // 64
    float* ss2    = fws + 1104;     // 64  (ends at float 1168 = byte 4672)
    bf16* ww2b = (bf16*)((char*)d_ws + 6144);          // 1024 bf16 = 2048 B (ends at 8192)
    bf16* Wcat = (bf16*)((char*)d_ws + 8192);          // 768*256 bf16 = 393216 B
    bf16* xq = (bf16*)((char*)d_ws + 401408);
    bf16* xk = xq + (size_t)NPTS * CH;
    bf16* xv = xk + (size_t)NPTS * CH;
    bf16* y2 = xv + (size_t)NPTS * CH;                 // CNT*32 bf16 (64 MB)
    float4* r4 = (float4*)(y2 + (size_t)CNT * 32);     // CNT float4
    // xb (bf16 x, 32 MB) aliases the y2 region: needed only between convw
    // and gemm; y2 is first written much later (stats2).
    bf16* xb = y2;
    // total ~185 MB

    hipMemsetAsync(d_ws, 0, 8192, stream);

    convw_kernel<<<97 + 8192, 256, 0, stream>>>(wq, wk, wv, ww2, x, Wcat, ww2b, xb);
    gemm_kernel<<<dim3(512, 6), 256, 0, stream>>>(xb, Wcat, bq, bk, bv, xq, xk, xv);
    statsp_kernel<<<1024, 256, 0, stream>>>(p, idx, wp1, bp1, statsP, r4);
    finalize_kernel<<<1, 256, 0, stream>>>(statsP, gp, btp, ssP, 3);
    computer_kernel<<<1024, 256, 0, stream>>>(ssP, r4);
    stats1_kernel<<<1024, 256, 0, stream>>>(idx, r4, xk, xq, wp2, bp2, stats1);
    finalize_kernel<<<1, 256, 0, stream>>>(stats1, g1, b1, ss1, 256);
    stats2_kernel<<<1024, 256, 0, stream>>>(idx, r4, xk, xq, wp2, bp2, ss1, ww1, bw1, y2, stats2);
    finalize_kernel<<<1, 256, 0, stream>>>(stats2, g2, b2, ss2, 32);
    final_kernel<<<NPTS / 32, 256, 0, stream>>>(idx, r4, xv, wp2, bp2, y2, ss2, ww2b, bw2, out);
}

// Round 7
// 663.571 us; speedup vs baseline: 1.4185x; 1.4185x over previous
//
#include <hip/hip_runtime.h>
#include <hip/hip_bf16.h>

#define NPTS 65536
#define NSAMP 16
#define CH 256
#define CNT (NPTS * NSAMP)   // 1048576
#define EPSV 1e-5f

typedef __hip_bfloat16 bf16;
typedef __attribute__((ext_vector_type(8))) short short8;
typedef __attribute__((ext_vector_type(4))) short sh4;
typedef __attribute__((ext_vector_type(4))) float floatx4;

__device__ __forceinline__ float b2f(bf16 v) { return __bfloat162float(v); }

// bf16 bits (as short) -> float
__device__ __forceinline__ float s2f(short v) {
    return __uint_as_float(((unsigned)(unsigned short)v) << 16);
}

__device__ __forceinline__ short f2bf_bits(float f) {
    bf16 h = __float2bfloat16(f);
    short s;
    __builtin_memcpy(&s, &h, 2);
    return s;
}

// ---------------------------------------------------------------------------
// convw: blocks 0..95 pack wq|wk|wv (f32) into Wcat[768*256] bf16; block 96
// converts ww2 (32x32) to bf16; blocks 97.. convert x (65536x256 f32) to xb
// bf16 (aliased onto the y2 workspace region - dead until stats2 writes y2).
// ---------------------------------------------------------------------------
__global__ __launch_bounds__(256) void convw_kernel(
    const float* __restrict__ wq, const float* __restrict__ wk,
    const float* __restrict__ wv, const float* __restrict__ ww2,
    const float* __restrict__ x,
    bf16* __restrict__ Wcat, bf16* __restrict__ ww2b, bf16* __restrict__ xb)
{
    if (blockIdx.x < 96) {
        int e = (blockIdx.x * 256 + threadIdx.x) * 8;   // e < 196608
        const float* src = (e < 65536) ? wq : (e < 131072) ? wk : wv;
        int off = e & 65535;
        float4 f0 = *(const float4*)(src + off);
        float4 f1 = *(const float4*)(src + off + 4);
        short8 r;
        r[0] = f2bf_bits(f0.x); r[1] = f2bf_bits(f0.y);
        r[2] = f2bf_bits(f0.z); r[3] = f2bf_bits(f0.w);
        r[4] = f2bf_bits(f1.x); r[5] = f2bf_bits(f1.y);
        r[6] = f2bf_bits(f1.z); r[7] = f2bf_bits(f1.w);
        *(short8*)(Wcat + e) = r;
    } else if (blockIdx.x == 96) {
        int e = threadIdx.x * 4;   // 256*4 = 1024 = 32*32
        float4 f = *(const float4*)(ww2 + e);
        sh4 r;
        r[0] = f2bf_bits(f.x); r[1] = f2bf_bits(f.y);
        r[2] = f2bf_bits(f.z); r[3] = f2bf_bits(f.w);
        *(sh4*)(ww2b + e) = r;
    } else {
        // x -> bf16: 16,777,216 elements, 8 per thread, 8192 blocks
        size_t e = ((size_t)(blockIdx.x - 97) * 256 + threadIdx.x) * 8;
        float4 f0 = *(const float4*)(x + e);
        float4 f1 = *(const float4*)(x + e + 4);
        short8 r;
        r[0] = f2bf_bits(f0.x); r[1] = f2bf_bits(f0.y);
        r[2] = f2bf_bits(f0.z); r[3] = f2bf_bits(f0.w);
        r[4] = f2bf_bits(f1.x); r[5] = f2bf_bits(f1.y);
        r[6] = f2bf_bits(f1.z); r[7] = f2bf_bits(f1.w);
        *(short8*)(xb + e) = r;
    }
}

// ---------------------------------------------------------------------------
// gemm: C[65536 x 768] = xb(bf16) @ Wcat^T, written as xq|xk|xv bf16 slices.
// 128x128 tiles, BK=32, LDS stride 40 (pad), 4 waves each 64x64.
// ---------------------------------------------------------------------------
__global__ __launch_bounds__(256) void gemm_kernel(
    const bf16* __restrict__ xb, const bf16* __restrict__ Wcat,
    const float* __restrict__ bq, const float* __restrict__ bk,
    const float* __restrict__ bv,
    bf16* __restrict__ xq, bf16* __restrict__ xk, bf16* __restrict__ xv)
{
    __shared__ __align__(16) bf16 As[128 * 40];
    __shared__ __align__(16) bf16 Bs[128 * 40];

    int t = threadIdx.x, lane = t & 63, wave = t >> 6;
    int m0 = blockIdx.x * 128;
    int y = blockIdx.y, n0 = y * 128;
    int srow = t >> 1, sch = t & 1;       // staging: 2 threads per row, 16 elems each
    int m = lane & 15, q = lane >> 4;
    int wm = wave >> 1, wn = wave & 1;

    floatx4 acc[4][4];
#pragma unroll
    for (int a = 0; a < 4; a++)
#pragma unroll
        for (int b = 0; b < 4; b++) acc[a][b] = (floatx4){0.f, 0.f, 0.f, 0.f};

    for (int kk = 0; kk < 256; kk += 32) {
        // stage A (bf16 copy)
        const bf16* ap = xb + (size_t)(m0 + srow) * 256 + kk + sch * 16;
        *(short8*)&As[srow * 40 + sch * 16]     = *(const short8*)ap;
        *(short8*)&As[srow * 40 + sch * 16 + 8] = *(const short8*)(ap + 8);
        // stage B (bf16 copy)
        const bf16* bp = Wcat + (size_t)(n0 + srow) * 256 + kk + sch * 16;
        *(short8*)&Bs[srow * 40 + sch * 16]     = *(const short8*)bp;
        *(short8*)&Bs[srow * 40 + sch * 16 + 8] = *(const short8*)(bp + 8);
        __syncthreads();

        short8 av[4], bvv[4];
#pragma unroll
        for (int mt = 0; mt < 4; mt++)
            av[mt] = *(const short8*)&As[(wm * 64 + mt * 16 + m) * 40 + q * 8];
#pragma unroll
        for (int nt = 0; nt < 4; nt++)
            bvv[nt] = *(const short8*)&Bs[(wn * 64 + nt * 16 + m) * 40 + q * 8];
#pragma unroll
        for (int mt = 0; mt < 4; mt++)
#pragma unroll
            for (int nt = 0; nt < 4; nt++)
                acc[mt][nt] = __builtin_amdgcn_mfma_f32_16x16x32_bf16(av[mt], bvv[nt], acc[mt][nt], 0, 0, 0);
        __syncthreads();
    }

    int z = y >> 1;
    bf16* O        = (z == 0) ? xq : (z == 1) ? xk : xv;
    const float* B = (z == 0) ? bq : (z == 1) ? bk : bv;
    int cbase = (y & 1) * 128 + wn * 64;
#pragma unroll
    for (int nt = 0; nt < 4; nt++) {
        int oc = cbase + nt * 16 + m;
        float bias = B[oc];
#pragma unroll
        for (int mt = 0; mt < 4; mt++) {
            int grow = m0 + wm * 64 + mt * 16 + q * 4;
#pragma unroll
            for (int i = 0; i < 4; i++)
                O[(size_t)(grow + i) * 256 + oc] = __float2bfloat16(acc[mt][nt][i] + bias);
        }
    }
}

// ---------------------------------------------------------------------------
// statsp: BN_p stats over p_r1 = (p[idx]-p) @ wp1^T + bp1 (3 channels);
// caches pre-BN v into v4[r]. Atomic fix: wave partials -> LDS -> 6 atomics
// per BLOCK (was 6 per wave = same-line serialization, 322us of stall), and
// the 6 accumulators live on separate cache lines (statsP[k*16]).
// ---------------------------------------------------------------------------
__global__ __launch_bounds__(256) void statsp_kernel(
    const float* __restrict__ p, const int* __restrict__ idx,
    const float* __restrict__ wp1, const float* __restrict__ bp1,
    float* __restrict__ statsP, float4* __restrict__ v4)
{
    __shared__ float red[4][6];

    float W00 = wp1[0], W01 = wp1[1], W02 = wp1[2];
    float W10 = wp1[3], W11 = wp1[4], W12 = wp1[5];
    float W20 = wp1[6], W21 = wp1[7], W22 = wp1[8];
    float B0 = bp1[0], B1 = bp1[1], B2 = bp1[2];

    float s0 = 0, s1 = 0, s2 = 0, q0 = 0, q1 = 0, q2 = 0;
    int stride = gridDim.x * blockDim.x;
    for (int r = blockIdx.x * blockDim.x + threadIdx.x; r < CNT; r += stride) {
        int n = r >> 4;
        int i = idx[r];
        float a0 = p[3 * (size_t)i]     - p[3 * (size_t)n];
        float a1 = p[3 * (size_t)i + 1] - p[3 * (size_t)n + 1];
        float a2 = p[3 * (size_t)i + 2] - p[3 * (size_t)n + 2];
        float v0 = W00 * a0 + W01 * a1 + W02 * a2 + B0;
        float v1 = W10 * a0 + W11 * a1 + W12 * a2 + B1;
        float v2 = W20 * a0 + W21 * a1 + W22 * a2 + B2;
        s0 += v0; q0 += v0 * v0;
        s1 += v1; q1 += v1 * v1;
        s2 += v2; q2 += v2 * v2;
        v4[r] = make_float4(v0, v1, v2, 0.f);
    }
    float v[6] = {s0, s1, s2, q0, q1, q2};
    int wave = threadIdx.x >> 6;
#pragma unroll
    for (int k = 0; k < 6; k++) {
        float xv = v[k];
#pragma unroll
        for (int off = 32; off > 0; off >>= 1) xv += __shfl_down(xv, off);
        if ((threadIdx.x & 63) == 0) red[wave][k] = xv;
    }
    __syncthreads();
    if (threadIdx.x < 6) {
        float s = red[0][threadIdx.x] + red[1][threadIdx.x]
                + red[2][threadIdx.x] + red[3][threadIdx.x];
        atomicAdd(&statsP[threadIdx.x * 16], s);   // separate cache lines
    }
}

// ---------------------------------------------------------------------------
// finalize: mean/var -> scale/shift (stride between channel accumulators)
// ---------------------------------------------------------------------------
__global__ void finalize_kernel(const float* __restrict__ stats,
                                const float* __restrict__ gamma,
                                const float* __restrict__ beta,
                                float* __restrict__ ss, int nch, int sstr)
{
    int c = threadIdx.x;
    if (c < nch) {
        float inv = 1.0f / (float)CNT;
        float mean = stats[c * sstr] * inv;
        float var = stats[(nch + c) * sstr] * inv - mean * mean;
        float sc = gamma[c] * rsqrtf(var + EPSV);
        ss[c] = sc;
        ss[nch + c] = beta[c] - mean * sc;
    }
}

// ---------------------------------------------------------------------------
// computer: r4[r] = relu(BN_p(v4[r])) in place (pure streaming transform)
// ---------------------------------------------------------------------------
__global__ __launch_bounds__(256) void computer_kernel(
    const float* __restrict__ ssP, float4* __restrict__ r4)
{
    float sc0 = ssP[0], sc1 = ssP[1], sc2 = ssP[2];
    float sh0 = ssP[3], sh1 = ssP[4], sh2 = ssP[5];

    int stride = gridDim.x * blockDim.x;
    for (int r = blockIdx.x * blockDim.x + threadIdx.x; r < CNT; r += stride) {
        float4 v = r4[r];
        float v0 = fmaxf(sc0 * v.x + sh0, 0.f);
        float v1 = fmaxf(sc1 * v.y + sh1, 0.f);
        float v2 = fmaxf(sc2 * v.z + sh2, 0.f);
        r4[r] = make_float4(v0, v1, v2, 0.f);
    }
}

// ---------------------------------------------------------------------------
// stats1: BN1 stats over w = xk[idx] - xq + p_r2.  Thread = 8 channels,
// short8 gathers, LDS block-reduce, 2 atomics/thread-channel.
// ---------------------------------------------------------------------------
__global__ __launch_bounds__(256) void stats1_kernel(
    const int* __restrict__ idx, const float4* __restrict__ r4,
    const bf16* __restrict__ xk, const bf16* __restrict__ xq,
    const float* __restrict__ wp2, const float* __restrict__ bp2,
    float* __restrict__ stats1)
{
    __shared__ int idxs[1024];
    __shared__ float redS[8 * 264];
    __shared__ float redQ[8 * 264];

    int t = threadIdx.x;
    int r0 = blockIdx.x * 1024;
    for (int e = t; e < 1024; e += 256) idxs[e] = idx[r0 + e];

    int sub = t & 31, rl = t >> 5, cb = sub * 8;
    float w0[8], w1[8], w2[8], bc[8];
#pragma unroll
    for (int k = 0; k < 8; k++) {
        w0[k] = wp2[3 * (cb + k)];
        w1[k] = wp2[3 * (cb + k) + 1];
        w2[k] = wp2[3 * (cb + k) + 2];
        bc[k] = bp2[cb + k];
    }
    float s8[8] = {0, 0, 0, 0, 0, 0, 0, 0};
    float q8[8] = {0, 0, 0, 0, 0, 0, 0, 0};
    __syncthreads();

#pragma unroll 4
    for (int rr = rl; rr < 1024; rr += 8) {
        int r = r0 + rr;
        int i = idxs[rr];
        float4 rv = r4[r];
        short8 kv = *(const short8*)(xk + (size_t)i * 256 + cb);
        short8 qv = *(const short8*)(xq + (size_t)(r >> 4) * 256 + cb);
#pragma unroll
        for (int k = 0; k < 8; k++) {
            float w = s2f(kv[k]) - s2f(qv[k]) + rv.x * w0[k] + rv.y * w1[k] + rv.z * w2[k] + bc[k];
            s8[k] += w; q8[k] += w * w;
        }
    }
#pragma unroll
    for (int k = 0; k < 8; k++) {
        redS[rl * 264 + cb + k] = s8[k];
        redQ[rl * 264 + cb + k] = q8[k];
    }
    __syncthreads();
    int c = t;
    float ts = 0, tq = 0;
#pragma unroll
    for (int sr = 0; sr < 8; sr++) {
        ts += redS[sr * 264 + c];
        tq += redQ[sr * 264 + c];
    }
    atomicAdd(&stats1[c], ts);
    atomicAdd(&stats1[256 + c], tq);
}

// ---------------------------------------------------------------------------
// stats2 (single-barrier double-buffer): y2 = relu(BN1(w)) @ ww1^T + bw1
// + BN2 stats. Two 32KB hb buffers, ONE __syncthreads per 64-row tile.
// ww1 B-fragments in VGPRs; BN1 consts folded in regs.
// ---------------------------------------------------------------------------
__global__ __launch_bounds__(256) void stats2_kernel(
    const int* __restrict__ idx, const float4* __restrict__ r4,
    const bf16* __restrict__ xk, const bf16* __restrict__ xq,
    const float* __restrict__ wp2, const float* __restrict__ bp2,
    const float* __restrict__ ss1,
    const float* __restrict__ ww1, const float* __restrict__ bw1,
    bf16* __restrict__ y2, float* __restrict__ stats2)
{
    __shared__ __align__(16) bf16 hb0[64 * 256];   // XOR-swizzled rows
    __shared__ __align__(16) bf16 hb1[64 * 256];

    int t = threadIdx.x;
    int lane = t & 63, wave = t >> 6;
    int m = lane & 15, q = lane >> 4;
    int sub = t & 31, rl = t >> 5, cb = sub * 8;
    int r0 = blockIdx.x * 1024;

    // ww1 B-fragments -> registers (f32 global, L2-resident, once per block)
    short8 bf0[8], bf1[8];
#pragma unroll
    for (int k = 0; k < 8; k++) {
        const float* w0p = ww1 + m * 256 + k * 32 + q * 8;
        const float* w1p = ww1 + (16 + m) * 256 + k * 32 + q * 8;
        float4 u0 = *(const float4*)(w0p);
        float4 u1 = *(const float4*)(w0p + 4);
        float4 u2 = *(const float4*)(w1p);
        float4 u3 = *(const float4*)(w1p + 4);
        short8 b0, b1;
        b0[0] = f2bf_bits(u0.x); b0[1] = f2bf_bits(u0.y);
        b0[2] = f2bf_bits(u0.z); b0[3] = f2bf_bits(u0.w);
        b0[4] = f2bf_bits(u1.x); b0[5] = f2bf_bits(u1.y);
        b0[6] = f2bf_bits(u1.z); b0[7] = f2bf_bits(u1.w);
        b1[0] = f2bf_bits(u2.x); b1[1] = f2bf_bits(u2.y);
        b1[2] = f2bf_bits(u2.z); b1[3] = f2bf_bits(u2.w);
        b1[4] = f2bf_bits(u3.x); b1[5] = f2bf_bits(u3.y);
        b1[6] = f2bf_bits(u3.z); b1[7] = f2bf_bits(u3.w);
        bf0[k] = b0; bf1[k] = b1;
    }

    float w0[8], w1[8], w2[8], bc[8], s1c[8], t1c[8];
#pragma unroll
    for (int k = 0; k < 8; k++) {
        w0[k] = wp2[3 * (cb + k)];
        w1[k] = wp2[3 * (cb + k) + 1];
        w2[k] = wp2[3 * (cb + k) + 2];
        bc[k] = bp2[cb + k];
        s1c[k] = ss1[cb + k];
        t1c[k] = ss1[256 + cb + k];
    }
    float bw0 = bw1[m], bw16 = bw1[16 + m];
    float jsum0 = 0, jsum1 = 0, jsq0 = 0, jsq1 = 0;
    int swh = cb ^ (rl << 3);        // staging write col (rr&7 == rl, const)
    int swa = (m & 7) << 3;          // MFMA read XOR ((wave*16+m)&7 == m&7)

    // prologue: stage tile 0 into hb0 (combined load+compute+write)
    {
#pragma unroll
        for (int u = 0; u < 8; u++) {
            int rr = rl + u * 8;
            int r = r0 + rr;
            int i = idx[r];
            float4 rv = r4[r];
            short8 kv = *(const short8*)(xk + (size_t)i * 256 + cb);
            short8 qv = *(const short8*)(xq + (size_t)(r >> 4) * 256 + cb);
            short8 h;
#pragma unroll
            for (int k = 0; k < 8; k++) {
                float w = s2f(kv[k]) - s2f(qv[k]) + rv.x * w0[k] + rv.y * w1[k] + rv.z * w2[k] + bc[k];
                h[k] = f2bf_bits(fmaxf(s1c[k] * w + t1c[k], 0.f));
            }
            *(short8*)&hb0[rr * 256 + swh] = h;
        }
    }

    for (int it = 0; it < 16; ++it) {
        __syncthreads();   // staging of tile `it` complete (from prev iter / prologue)

        int rbn = r0 + (it + 1) * 64;
        bf16* hbw = (it & 1) ? hb0 : hb1;                 // next buffer
        const bf16* abase = ((it & 1) ? hb1 : hb0) + (wave * 16 + m) * 256;

        // A: issue next tile's random xk gathers (latency hides under B)
        short8 kvs[8];
        if (it < 15) {
#pragma unroll
            for (int u = 0; u < 8; u++) {
                int r = rbn + rl + u * 8;
                kvs[u] = *(const short8*)(xk + (size_t)idx[r] * 256 + cb);
            }
        }

        // B: MFMA from current buffer + y2 stores
        floatx4 a0 = (floatx4){bw0, bw0, bw0, bw0};
        floatx4 a1 = (floatx4){bw16, bw16, bw16, bw16};
#pragma unroll
        for (int k = 0; k < 8; k++) {
            int col = (k * 32 + q * 8) ^ swa;
            short8 af = *(const short8*)(abase + col);
            a0 = __builtin_amdgcn_mfma_f32_16x16x32_bf16(af, bf0[k], a0, 0, 0, 0);
            a1 = __builtin_amdgcn_mfma_f32_16x16x32_bf16(af, bf1[k], a1, 0, 0, 0);
        }
        int grow = r0 + it * 64 + wave * 16 + q * 4;
#pragma unroll
        for (int ii = 0; ii < 4; ii++) {
            float y0 = a0[ii];
            float y1 = a1[ii];
            jsum0 += y0; jsq0 += y0 * y0;
            jsum1 += y1; jsq1 += y1 * y1;
            y2[(size_t)(grow + ii) * 32 + m]      = __float2bfloat16(y0);
            y2[(size_t)(grow + ii) * 32 + 16 + m] = __float2bfloat16(y1);
        }

        // C: finish next tile's rows (cache-friendly loads) and write to LDS
        if (it < 15) {
#pragma unroll
            for (int u = 0; u < 8; u++) {
                int rr = rl + u * 8;
                int r = rbn + rr;
                float4 rv = r4[r];
                short8 qv = *(const short8*)(xq + (size_t)(r >> 4) * 256 + cb);
                short8 h;
#pragma unroll
                for (int k = 0; k < 8; k++) {
                    float w = s2f(kvs[u][k]) - s2f(qv[k]) + rv.x * w0[k] + rv.y * w1[k] + rv.z * w2[k] + bc[k];
                    h[k] = f2bf_bits(fmaxf(s1c[k] * w + t1c[k], 0.f));
                }
                *(short8*)&hbw[rr * 256 + swh] = h;
            }
        }
    }

    jsum0 += __shfl_xor(jsum0, 16); jsum0 += __shfl_xor(jsum0, 32);
    jsum1 += __shfl_xor(jsum1, 16); jsum1 += __shfl_xor(jsum1, 32);
    jsq0  += __shfl_xor(jsq0, 16);  jsq0  += __shfl_xor(jsq0, 32);
    jsq1  += __shfl_xor(jsq1, 16);  jsq1  += __shfl_xor(jsq1, 32);
    if (q == 0) {
        atomicAdd(&stats2[m], jsum0);
        atomicAdd(&stats2[16 + m], jsum1);
        atomicAdd(&stats2[32 + m], jsq0);
        atomicAdd(&stats2[48 + m], jsq1);
    }
}

// ---------------------------------------------------------------------------
// final: wave-per-point, zero barriers.
// ---------------------------------------------------------------------------
__global__ __launch_bounds__(256) void final_kernel(
    const int* __restrict__ idx, const float4* __restrict__ r4,
    const bf16* __restrict__ xv,
    const float* __restrict__ wp2, const float* __restrict__ bp2,
    const bf16* __restrict__ y2, const float* __restrict__ ss2,
    const bf16* __restrict__ ww2b, const float* __restrict__ bw2,
    float* __restrict__ out)
{
    __shared__ __align__(16) float wsm[4][16][36];  // [wave][s][j] stride 36 (144B, 16-aligned)
    __shared__ float Asm[4][4][32];                 // [wave][d][j]

    int t = threadIdx.x, wave = t >> 6, lane = t & 63;
    int m = lane & 15, q = lane >> 4;

    // logits B-fragments: ww2b rows m / 16+m (output cols), K-span q*8
    short8 bf0 = *(const short8*)(ww2b + m * 32 + q * 8);
    short8 bf1 = *(const short8*)(ww2b + (16 + m) * 32 + q * 8);
    float bwj0 = bw2[m], bwj1 = bw2[16 + m];

    float s2c[8], t2c[8];
#pragma unroll
    for (int k = 0; k < 8; k++) {
        s2c[k] = ss2[q * 8 + k];
        t2c[k] = ss2[32 + q * 8 + k];
    }

    int c0 = lane * 4;          // this lane's 4 output channels
    int j4 = (lane & 7) * 4;    // j = c & 31
    float wpc0[4], wpc1[4], wpc2[4], bpc[4];
#pragma unroll
    for (int k = 0; k < 4; k++) {
        wpc0[k] = wp2[(c0 + k) * 3];
        wpc1[k] = wp2[(c0 + k) * 3 + 1];
        wpc2[k] = wp2[(c0 + k) * 3 + 2];
        bpc[k]  = bp2[c0 + k];
    }

    int pbase = (blockIdx.x * 4 + wave) * 8;
    for (int pp = 0; pp < 8; pp++) {
        int n = pbase + pp;
        size_t rbase = (size_t)n * 16;

        int iv = idx[rbase + m];   // lanes 0..15 hold the 16 neighbor ids

        // A-frag: z[s=m][u=q*8+k] = relu(bn2(y2))
        short8 yv = *(const short8*)(y2 + (rbase + m) * 32 + q * 8);
        short8 av;
#pragma unroll
        for (int k = 0; k < 8; k++)
            av[k] = f2bf_bits(fmaxf(s2c[k] * s2f(yv[k]) + t2c[k], 0.f));

        floatx4 l0 = (floatx4){bwj0, bwj0, bwj0, bwj0};
        floatx4 l1 = (floatx4){bwj1, bwj1, bwj1, bwj1};
        l0 = __builtin_amdgcn_mfma_f32_16x16x32_bf16(av, bf0, l0, 0, 0, 0);
        l1 = __builtin_amdgcn_mfma_f32_16x16x32_bf16(av, bf1, l1, 0, 0, 0);
        // lane (m,q), reg i: l0[i] = lb[s=q*4+i][j=m], l1[i] = lb[s][j=16+m]

        // softmax over s per column j: lanes {m, m+16, m+32, m+48} hold a column
        float mx0 = fmaxf(fmaxf(l0[0], l0[1]), fmaxf(l0[2], l0[3]));
        float mx1 = fmaxf(fmaxf(l1[0], l1[1]), fmaxf(l1[2], l1[3]));
        mx0 = fmaxf(mx0, __shfl_xor(mx0, 16));
        mx0 = fmaxf(mx0, __shfl_xor(mx0, 32));
        mx1 = fmaxf(mx1, __shfl_xor(mx1, 16));
        mx1 = fmaxf(mx1, __shfl_xor(mx1, 32));
        float w0[4], w1[4];
        float sum0 = 0.f, sum1 = 0.f;
#pragma unroll
        for (int i = 0; i < 4; i++) {
            w0[i] = __expf(l0[i] - mx0); sum0 += w0[i];
            w1[i] = __expf(l1[i] - mx1); sum1 += w1[i];
        }
        sum0 += __shfl_xor(sum0, 16); sum0 += __shfl_xor(sum0, 32);
        sum1 += __shfl_xor(sum1, 16); sum1 += __shfl_xor(sum1, 32);
        float inv0 = 1.f / sum0, inv1 = 1.f / sum1;

        // normalize + A[d][j] partials + stash w to LDS
        float A00 = 0, A10 = 0, A20 = 0, A30 = 0;
        float A01 = 0, A11 = 0, A21 = 0, A31 = 0;
#pragma unroll
        for (int i = 0; i < 4; i++) {
            w0[i] *= inv0; w1[i] *= inv1;
            float4 rv = r4[rbase + q * 4 + i];
            A00 += rv.x * w0[i]; A10 += rv.y * w0[i];
            A20 += rv.z * w0[i]; A30 += w0[i];
            A01 += rv.x * w1[i]; A11 += rv.y * w1[i];
            A21 += rv.z * w1[i]; A31 += w1[i];
            wsm[wave][q * 4 + i][m]      = w0[i];
            wsm[wave][q * 4 + i][16 + m] = w1[i];
        }
        A00 += __shfl_xor(A00, 16); A00 += __shfl_xor(A00, 32);
        A10 += __shfl_xor(A10, 16); A10 += __shfl_xor(A10, 32);
        A20 += __shfl_xor(A20, 16); A20 += __shfl_xor(A20, 32);
        A30 += __shfl_xor(A30, 16); A30 += __shfl_xor(A30, 32);
        A01 += __shfl_xor(A01, 16); A01 += __shfl_xor(A01, 32);
        A11 += __shfl_xor(A11, 16); A11 += __shfl_xor(A11, 32);
        A21 += __shfl_xor(A21, 16); A21 += __shfl_xor(A21, 32);
        A31 += __shfl_xor(A31, 16); A31 += __shfl_xor(A31, 32);
        if (q == 0) {
            Asm[wave][0][m] = A00; Asm[wave][1][m] = A10;
            Asm[wave][2][m] = A20; Asm[wave][3][m] = A30;
            Asm[wave][0][16 + m] = A01; Asm[wave][1][16 + m] = A11;
            Asm[wave][2][16 + m] = A21; Asm[wave][3][16 + m] = A31;
        }
        // wave-private LDS: in-order DS pipe + compiler lgkmcnt ordering,
        // no __syncthreads needed.

        // phase D: weighted neighbor sum over the gathered xv rows
        float acc0 = 0, acc1 = 0, acc2 = 0, acc3 = 0;
#pragma unroll
        for (int s = 0; s < 16; s++) {
            int i = __builtin_amdgcn_readlane(iv, s);   // uniform -> SGPR base
            sh4 vv = *(const sh4*)(xv + (size_t)i * 256 + c0);
            float4 wv = *(const float4*)&wsm[wave][s][j4];
            acc0 += s2f(vv[0]) * wv.x;
            acc1 += s2f(vv[1]) * wv.y;
            acc2 += s2f(vv[2]) * wv.z;
            acc3 += s2f(vv[3]) * wv.w;
        }

        float res[4] = {acc0, acc1, acc2, acc3};
#pragma unroll
        for (int k = 0; k < 4; k++) {
            int j = j4 + k;
            res[k] += wpc0[k] * Asm[wave][0][j] + wpc1[k] * Asm[wave][1][j]
                    + wpc2[k] * Asm[wave][2][j] + bpc[k]  * Asm[wave][3][j];
        }
        *(float4*)(out + (size_t)n * 256 + c0) =
            make_float4(res[0], res[1], res[2], res[3]);
    }
}

// ---------------------------------------------------------------------------
extern "C" void kernel_launch(void* const* d_in, const int* in_sizes, int n_in,
                              void* d_out, int out_size, void* d_ws, size_t ws_size,
                              hipStream_t stream) {
    (void)in_sizes; (void)n_in; (void)out_size; (void)ws_size;

    const float* p   = (const float*)d_in[0];
    const float* x   = (const float*)d_in[1];
    const int*   idx = (const int*)d_in[2];
    const float* wq  = (const float*)d_in[3];  const float* bq  = (const float*)d_in[4];
    const float* wk  = (const float*)d_in[5];  const float* bk  = (const float*)d_in[6];
    const float* wv  = (const float*)d_in[7];  const float* bv  = (const float*)d_in[8];
    const float* wp1 = (const float*)d_in[9];  const float* bp1 = (const float*)d_in[10];
    const float* gp  = (const float*)d_in[11]; const float* btp = (const float*)d_in[12];
    const float* wp2 = (const float*)d_in[13]; const float* bp2 = (const float*)d_in[14];
    const float* g1  = (const float*)d_in[15]; const float* b1  = (const float*)d_in[16];
    const float* ww1 = (const float*)d_in[17]; const float* bw1 = (const float*)d_in[18];
    const float* g2  = (const float*)d_in[19]; const float* b2  = (const float*)d_in[20];
    const float* ww2 = (const float*)d_in[21]; const float* bw2 = (const float*)d_in[22];
    float* out = (float*)d_out;

    // workspace layout
    float* fws    = (float*)d_ws;
    float* statsP = fws;            // 96 floats: 6 accumulators at stride 16
    float* ssP    = fws + 96;       // 6
    float* stats1 = fws + 112;      // 512
    float* ss1    = fws + 624;      // 512
    float* stats2 = fws + 1136;     // 64
    float* ss2    = fws + 1200;     // 64  (ends at float 1264 = byte 5056)
    bf16* ww2b = (bf16*)((char*)d_ws + 6144);          // 1024 bf16 = 2048 B (ends at 8192)
    bf16* Wcat = (bf16*)((char*)d_ws + 8192);          // 768*256 bf16 = 393216 B
    bf16* xq = (bf16*)((char*)d_ws + 401408);
    bf16* xk = xq + (size_t)NPTS * CH;
    bf16* xv = xk + (size_t)NPTS * CH;
    bf16* y2 = xv + (size_t)NPTS * CH;                 // CNT*32 bf16 (64 MB)
    float4* r4 = (float4*)(y2 + (size_t)CNT * 32);     // CNT float4
    // xb (bf16 x, 32 MB) aliases the y2 region: needed only between convw
    // and gemm; y2 is first written much later (stats2).
    bf16* xb = y2;
    // total ~185 MB

    hipMemsetAsync(d_ws, 0, 8192, stream);

    convw_kernel<<<97 + 8192, 256, 0, stream>>>(wq, wk, wv, ww2, x, Wcat, ww2b, xb);
    gemm_kernel<<<dim3(512, 6), 256, 0, stream>>>(xb, Wcat, bq, bk, bv, xq, xk, xv);
    statsp_kernel<<<1024, 256, 0, stream>>>(p, idx, wp1, bp1, statsP, r4);
    finalize_kernel<<<1, 256, 0, stream>>>(statsP, gp, btp, ssP, 3, 16);
    computer_kernel<<<1024, 256, 0, stream>>>(ssP, r4);
    stats1_kernel<<<1024, 256, 0, stream>>>(idx, r4, xk, xq, wp2, bp2, stats1);
    finalize_kernel<<<1, 256, 0, stream>>>(stats1, g1, b1, ss1, 256, 1);
    stats2_kernel<<<1024, 256, 0, stream>>>(idx, r4, xk, xq, wp2, bp2, ss1, ww1, bw1, y2, stats2);
    finalize_kernel<<<1, 256, 0, stream>>>(stats2, g2, b2, ss2, 32, 1);
    final_kernel<<<NPTS / 32, 256, 0, stream>>>(idx, r4, xv, wp2, bp2, y2, ss2, ww2b, bw2, out);
}